// Round 1
// 6087.944 us; speedup vs baseline: 1.0266x; 1.0266x over previous
//
#include <hip/hip_runtime.h>

#define Tn 512
#define Bn 64
#define In 300
#define Hn 1000
#define G4H 4000
#define KP 1024   // padded K for recurrence (H=1000 -> 1024)
#define KI 320    // padded K for input GEMM (I=300 -> 320)
#define NB 125    // scan blocks: 125 * 8 hidden cols = 1000
#define NGROUP 8  // barrier groups (ceil(125/16))

typedef __attribute__((ext_vector_type(8))) short bf16x8;
typedef __attribute__((ext_vector_type(4))) float f32x4;
typedef unsigned int u32;
typedef unsigned short u16;
typedef unsigned long long u64;

__device__ __forceinline__ u16 f2bf(float x) {
  union { float f; u32 u; } v; v.f = x;
  u32 r = (v.u + 0x7fffu + ((v.u >> 16) & 1u)) >> 16;
  return (u16)r;
}
__device__ __forceinline__ float bf2f(u16 s) {
  union { u32 u; float f; } v; v.u = ((u32)s) << 16;
  return v.f;
}
__device__ __forceinline__ float sigm(float x) { return 1.f / (1.f + __expf(-x)); }
__device__ __forceinline__ float tanh_f(float x) {
  float e = __expf(2.f * x);
  return 1.f - 2.f / (e + 1.f);
}

// Relaxed agent-scope accesses: routed to the coherent point (L3) per-access,
// with NO buffer_wbl2 / buffer_inv cache maintenance (that was the ~20us/step).
__device__ __forceinline__ u64 aload64(const u64* p) {
  return __hip_atomic_load((u64*)p, __ATOMIC_RELAXED, __HIP_MEMORY_SCOPE_AGENT);
}
__device__ __forceinline__ void astore64(u64* p, u64 v) {
  __hip_atomic_store(p, v, __ATOMIC_RELAXED, __HIP_MEMORY_SCOPE_AGENT);
}

// ---------------------------------------------------------------- converts
__global__ void conv_pad(const float* __restrict__ src, u16* __restrict__ dst,
                         int rows, int scols, int dcols) {
  int idx = blockIdx.x * 256 + threadIdx.x;
  int total = rows * dcols;
  if (idx >= total) return;
  int r = idx / dcols, k = idx - r * dcols;
  float v = (k < scols) ? src[(size_t)r * scols + k] : 0.f;
  dst[idx] = f2bf(v);
}

// init h double-buffer (bf16, K-padded with zeros) + zero the barrier area
__global__ void init_scan(const float* __restrict__ h0, u16* __restrict__ hbuf,
                          u32* __restrict__ bar) {
  int idx = blockIdx.x * 256 + threadIdx.x;
  if (idx < 4096) bar[idx] = 0;
  if (idx >= 2 * Bn * KP) return;
  int which = idx >> 16;          // 64*1024 = 65536 per buffer
  int rem = idx & 65535;
  int b = rem >> 10, k = rem & (KP - 1);
  float v = (which == 0 && k < Hn) ? h0[b * Hn + k] : 0.f;
  hbuf[idx] = f2bf(v);
}

// ---------------------------------------------------------------- xg GEMM
// Writes xg in scan-friendly layout: xg[t][nb][b][32], slot = g*8 + cc
// where hidden col j = 8*nb + cc, gate col n = g*1000 + j.
template<bool XF32>
__global__ void __launch_bounds__(256)
gemm_xg(const u16* __restrict__ A, const u16* __restrict__ Wb,
        const float* __restrict__ b_ih, const float* __restrict__ b_hh,
        void* __restrict__ xg_out) {
  const int lane = threadIdx.x & 63, w = threadIdx.x >> 6;
  const int m0 = blockIdx.x * 64, n0 = blockIdx.y * 64;
  f32x4 acc[4] = {};
  const int arow = m0 + w * 16 + (lane & 15);
  const int koff = (lane >> 4) * 8;
  int nrow[4];
#pragma unroll
  for (int nt = 0; nt < 4; ++nt) {
    int n = n0 + nt * 16 + (lane & 15);
    nrow[nt] = (n < G4H) ? n : (G4H - 1);
  }
  for (int kc = 0; kc < KI / 32; ++kc) {
    bf16x8 a = *(const bf16x8*)(A + (size_t)arow * KI + kc * 32 + koff);
#pragma unroll
    for (int nt = 0; nt < 4; ++nt) {
      bf16x8 bb = *(const bf16x8*)(Wb + (size_t)nrow[nt] * KI + kc * 32 + koff);
      acc[nt] = __builtin_amdgcn_mfma_f32_16x16x32_bf16(a, bb, acc[nt], 0, 0, 0);
    }
  }
#pragma unroll
  for (int nt = 0; nt < 4; ++nt) {
    int col = n0 + nt * 16 + (lane & 15);
    if (col >= G4H) continue;
    float bias = b_ih[col] + b_hh[col];
    u32 g = (u32)col / 1000u;
    int j = col - (int)g * 1000;
    int nb8 = j >> 3, cc = j & 7;
    int slot = ((int)g << 3) | cc;       // = jj in [0,32)
    int mrow = m0 + w * 16 + (lane >> 4) * 4;
#pragma unroll
    for (int r = 0; r < 4; ++r) {
      int m = mrow + r;
      int t = m >> 6, b = m & 63;
      float v = acc[nt][r] + bias;
      size_t o = (((size_t)t * NB + nb8) * 64 + b) * 32 + slot;
      if constexpr (XF32) ((float*)xg_out)[o] = v;
      else                ((u16*)xg_out)[o] = f2bf(v);
    }
  }
}

// ---------------------------------------------------------------- barrier
// Monotonic two-level barrier, 256-B-spaced lines, broadcast tree.
// ALL RELAXED: no release/acquire -> no L2 writeback/invalidate per step.
// Ordering is provided by __syncthreads (s_waitcnt vmcnt(0) before s_barrier)
// around the data stores/loads, which themselves bypass to the coherent point.
__device__ __forceinline__ void bar_arrive(u32* bar, u32 step) {
  const int g = (int)blockIdx.x >> 4;
  const int gsz0 = NB - (g << 4);
  const u32 gsz = (u32)(gsz0 < 16 ? gsz0 : 16);
  u32 old = __hip_atomic_fetch_add(bar + 64 + g * 64, 1u, __ATOMIC_RELAXED,
                                   __HIP_MEMORY_SCOPE_AGENT);
  if (old == gsz * step - 1u) {
    u32 r = __hip_atomic_fetch_add(bar, 1u, __ATOMIC_RELAXED,
                                   __HIP_MEMORY_SCOPE_AGENT);
    if (r == (u32)NGROUP * step - 1u) {
#pragma unroll
      for (int gg = 0; gg < NGROUP; ++gg)
        __hip_atomic_store(bar + 2048 + gg * 64, step, __ATOMIC_RELAXED,
                           __HIP_MEMORY_SCOPE_AGENT);
    }
  }
}
__device__ __forceinline__ void bar_wait(u32* bar, u32 step) {
  const int g = (int)blockIdx.x >> 4;
  u32* gen = bar + 2048 + g * 64;
  while (__hip_atomic_load(gen, __ATOMIC_RELAXED, __HIP_MEMORY_SCOPE_AGENT) < step) {
    __builtin_amdgcn_s_sleep(1);
  }
}

// ---------------------------------------------------------------- scan
// 125 blocks x 256 threads. Block nb owns hidden cols [8nb, 8nb+8).
// N-REUSE x2: each wave holds W_hh B-frags for 32 gate rows (2 N-tiles,
// 256 VGPR) so every h fragment loaded from L3 feeds TWO MFMAs.
// h broadcast traffic: 32 MB/step -> 16 MB/step; atomic ops 4M -> 2M/step.
// Inner loop is 8-kc double-buffered (>=16 loads in flight per wave).
template<bool XF32>
__global__ void __launch_bounds__(256, 1)
lstm_scan(const float* __restrict__ Whh, const float* __restrict__ c0,
          const void* __restrict__ xg_, u64* __restrict__ hbu,
          float* __restrict__ out, u32* __restrict__ bar) {
  __shared__ float Sc[4][16][33];
  __shared__ __align__(8) u16 hs[64][8];
  const int tid = threadIdx.x;
  const int lane = tid & 63;
  const int w = tid >> 6;
  const int nb = blockIdx.x;
  const int s = lane & 15;        // gate-row index within N-tile
  const int q = lane >> 4;        // k-quarter

  // ---- stage this lane's W_hh B-fragments for 2 N-tiles (once) ----
  // N-tile nt covers jj = nt*16 + s; gate g = jj>>3, col cc = jj&7,
  // global gate row = g*1000 + nb*8 + cc.
  bf16x8 wreg0[32], wreg1[32];
  {
    const int jj0 = s;
    const float* wrow0 =
        Whh + (size_t)((jj0 >> 3) * Hn + nb * 8 + (jj0 & 7)) * Hn;
    const int jj1 = 16 + s;
    const float* wrow1 =
        Whh + (size_t)((jj1 >> 3) * Hn + nb * 8 + (jj1 & 7)) * Hn;
#pragma unroll
    for (int kc = 0; kc < 32; ++kc) {
      const int k0 = kc * 32 + q * 8;
      bf16x8 v0, v1;
#pragma unroll
      for (int j = 0; j < 8; ++j) {
        float f0 = (k0 + j < Hn) ? wrow0[k0 + j] : 0.f;
        float f1 = (k0 + j < Hn) ? wrow1[k0 + j] : 0.f;
        v0[j] = (short)f2bf(f0);
        v1[j] = (short)f2bf(f1);
      }
      wreg0[kc] = v0;
      wreg1[kc] = v1;
    }
  }

  // elementwise lane mapping: 2 cells per lane: (batch-local bl+8k, col cc)
  const int bl = lane >> 3, cc = lane & 7;
  const int jh = nb * 8 + cc;
  float cst[2];
  cst[0] = c0[(size_t)(w * 16 + bl) * Hn + jh];
  cst[1] = c0[(size_t)(w * 16 + bl + 8) * Hn + jh];

  const float* xf = (const float*)xg_;
  const u16* xh = (const u16*)xg_;

  // prefetch xg for t=0 (C-layout: batch rows w*16+q*4+r, slot nt*16+s)
  float xa[8];
  {
    size_t base = (((size_t)0 * NB + nb) * 64 + w * 16 + q * 4) * 32 + s;
#pragma unroll
    for (int nt = 0; nt < 2; ++nt)
#pragma unroll
      for (int r = 0; r < 4; ++r) {
        size_t o = base + (size_t)r * 32 + nt * 16;
        xa[nt * 4 + r] = XF32 ? xf[o] : bf2f(xh[o]);
      }
  }

  // u64 geometry: one h buffer = Bn*KP/4 = 16384 u64; row stride 256 u64.
  for (int t = 0; t < Tn; ++t) {
    const u64* hc = hbu + (size_t)(t & 1) * 16384;
    u64* hn = hbu + (size_t)((t + 1) & 1) * 16384;
    const u64* hrow = hc + (size_t)(w * 16 + s) * 256 + q * 2;

    f32x4 a00 = {xa[0], xa[1], xa[2], xa[3]};
    f32x4 a01 = {0.f, 0.f, 0.f, 0.f};
    f32x4 a10 = {xa[4], xa[5], xa[6], xa[7]};
    f32x4 a11 = {0.f, 0.f, 0.f, 0.f};

    union U { u64 d[2]; bf16x8 v; };
    U b0[8], b1[8];
#pragma unroll
    for (int k = 0; k < 8; ++k) {
      b0[k].d[0] = aload64(hrow + k * 8);
      b0[k].d[1] = aload64(hrow + k * 8 + 1);
    }
#pragma unroll
    for (int k = 0; k < 8; ++k) {
      b1[k].d[0] = aload64(hrow + (8 + k) * 8);
      b1[k].d[1] = aload64(hrow + (8 + k) * 8 + 1);
    }
#pragma unroll
    for (int k = 0; k < 8; ++k) {
      a00 = __builtin_amdgcn_mfma_f32_16x16x32_bf16(b0[k].v, wreg0[k], a00, 0, 0, 0);
      a10 = __builtin_amdgcn_mfma_f32_16x16x32_bf16(b0[k].v, wreg1[k], a10, 0, 0, 0);
    }
#pragma unroll
    for (int k = 0; k < 8; ++k) {
      b0[k].d[0] = aload64(hrow + (16 + k) * 8);
      b0[k].d[1] = aload64(hrow + (16 + k) * 8 + 1);
    }
#pragma unroll
    for (int k = 0; k < 8; ++k) {
      a00 = __builtin_amdgcn_mfma_f32_16x16x32_bf16(b1[k].v, wreg0[8 + k], a00, 0, 0, 0);
      a10 = __builtin_amdgcn_mfma_f32_16x16x32_bf16(b1[k].v, wreg1[8 + k], a10, 0, 0, 0);
    }
#pragma unroll
    for (int k = 0; k < 8; ++k) {
      b1[k].d[0] = aload64(hrow + (24 + k) * 8);
      b1[k].d[1] = aload64(hrow + (24 + k) * 8 + 1);
    }
#pragma unroll
    for (int k = 0; k < 8; ++k) {
      a01 = __builtin_amdgcn_mfma_f32_16x16x32_bf16(b0[k].v, wreg0[16 + k], a01, 0, 0, 0);
      a11 = __builtin_amdgcn_mfma_f32_16x16x32_bf16(b0[k].v, wreg1[16 + k], a11, 0, 0, 0);
    }
#pragma unroll
    for (int k = 0; k < 8; ++k) {
      a01 = __builtin_amdgcn_mfma_f32_16x16x32_bf16(b1[k].v, wreg0[24 + k], a01, 0, 0, 0);
      a11 = __builtin_amdgcn_mfma_f32_16x16x32_bf16(b1[k].v, wreg1[24 + k], a11, 0, 0, 0);
    }

    // redistribute C within the wave via LDS (writer wave == reader wave)
#pragma unroll
    for (int r = 0; r < 4; ++r) {
      Sc[w][q * 4 + r][s]      = a00[r] + a01[r];
      Sc[w][q * 4 + r][16 + s] = a10[r] + a11[r];
    }

    float hv[2];
#pragma unroll
    for (int k = 0; k < 2; ++k) {
      int bb = bl + 8 * k;
      float gi = Sc[w][bb][cc];
      float gf = Sc[w][bb][8 + cc];
      float gg = Sc[w][bb][16 + cc];
      float go = Sc[w][bb][24 + cc];
      float iv = sigm(gi), fv = sigm(gf), gv = tanh_f(gg), ov = sigm(go);
      cst[k] = fv * cst[k] + iv * gv;
      hv[k] = ov * tanh_f(cst[k]);
      out[((size_t)t * Bn + (w * 16 + bb)) * Hn + jh] = hv[k];  // cached store
      hs[w * 16 + bb][cc] = f2bf(hv[k]);                        // stage bf16
    }

    if (t != Tn - 1) {
      __syncthreads();                           // hs visible block-wide
      if (tid < 128) {
        int row = tid >> 1, half = tid & 1;
        u64 hvv = *(const u64*)&hs[row][half * 4];   // 4 bf16 packed
        astore64(hn + (size_t)row * 256 + nb * 2 + half, hvv);
      }
      __syncthreads();                           // vmcnt(0): h at L3
      if (tid == 0) bar_arrive(bar, (u32)(t + 1));

      // overlap the barrier wait: next-step xg prefetch (normal loads)
      {
        size_t base =
            (((size_t)(t + 1) * NB + nb) * 64 + w * 16 + q * 4) * 32 + s;
#pragma unroll
        for (int nt = 0; nt < 2; ++nt)
#pragma unroll
          for (int r = 0; r < 4; ++r) {
            size_t o = base + (size_t)r * 32 + nt * 16;
            xa[nt * 4 + r] = XF32 ? xf[o] : bf2f(xh[o]);
          }
      }
      if (tid == 0) bar_wait(bar, (u32)(t + 1));
      __syncthreads();                           // release all waves into t+1
    }
  }
}

// ---------------------------------------------------------------- launch
extern "C" void kernel_launch(void* const* d_in, const int* in_sizes, int n_in,
                              void* d_out, int out_size, void* d_ws, size_t ws_size,
                              hipStream_t stream) {
  const float* inputs = (const float*)d_in[0];
  const float* h0 = (const float*)d_in[1];
  const float* c0 = (const float*)d_in[2];
  const float* W_ih = (const float*)d_in[3];
  const float* W_hh = (const float*)d_in[4];
  const float* b_ih = (const float*)d_in[5];
  const float* b_hh = (const float*)d_in[6];
  float* out = (float*)d_out;

  char* ws = (char*)d_ws;
  size_t off = 0;
  auto carve = [&](size_t bytes) {
    char* p = ws + off;
    off = (off + bytes + 255) & ~(size_t)255;
    return p;
  };
  u32* bar = (u32*)carve(16384);
  u16* in_bf = (u16*)carve((size_t)Tn * Bn * KI * 2);
  u16* wih_bf = (u16*)carve((size_t)G4H * KI * 2);
  u16* hbuf = (u16*)carve((size_t)2 * Bn * KP * 2);
  size_t fixed = off;
  size_t xg_f32 = (size_t)Tn * NB * 64 * 32 * 4;
  bool xf32 = (ws_size >= fixed + xg_f32);
  void* xg = (void*)carve(xf32 ? xg_f32 : xg_f32 / 2);

  int tot_in = Tn * Bn * KI;
  conv_pad<<<dim3((tot_in + 255) / 256), dim3(256), 0, stream>>>(
      inputs, in_bf, Tn * Bn, In, KI);
  int tot_w = G4H * KI;
  conv_pad<<<dim3((tot_w + 255) / 256), dim3(256), 0, stream>>>(
      W_ih, wih_bf, G4H, In, KI);
  init_scan<<<dim3(512), dim3(256), 0, stream>>>(h0, hbuf, bar);

  if (xf32) {
    gemm_xg<true><<<dim3(Tn * Bn / 64, (G4H + 63) / 64), dim3(256), 0, stream>>>(
        in_bf, wih_bf, b_ih, b_hh, xg);
    lstm_scan<true><<<dim3(NB), dim3(256), 0, stream>>>(
        W_hh, c0, xg, (u64*)hbuf, out, bar);
  } else {
    gemm_xg<false><<<dim3(Tn * Bn / 64, (G4H + 63) / 64), dim3(256), 0, stream>>>(
        in_bf, wih_bf, b_ih, b_hh, xg);
    lstm_scan<false><<<dim3(NB), dim3(256), 0, stream>>>(
        W_hh, c0, xg, (u64*)hbuf, out, bar);
  }
}